// Round 8
// baseline (1169.689 us; speedup 1.0000x reference)
//
#include <hip/hip_runtime.h>
#include <math.h>

#define B_ 64
#define T_ 1024
#define D_ 256
#define U_ 256

typedef _Float16 f16x4 __attribute__((ext_vector_type(4)));
typedef _Float16 f16x8 __attribute__((ext_vector_type(8)));
typedef float    f32x4 __attribute__((ext_vector_type(4)));

// ---------------------------------------------------------------------------
// Kernel 1: proj = inputs @ W_xh + b_h via MFMA f16 (UNCHANGED from R7 —
// passing, ~128 µs; its A/B/C fragment mappings are HW-verified by R7's pass).
// ---------------------------------------------------------------------------
#define PBM 64
#define PBN 64
#define PLD 40

__global__ __launch_bounds__(256, 2)
void proj_gemm(const float* __restrict__ A,      // [M, D_]
               const float* __restrict__ Bm,     // [D_, U_]
               const float* __restrict__ bias,   // [U_]
               float* __restrict__ C) {          // [M, U_]
    __shared__ _Float16 As[PBM][PLD];
    __shared__ _Float16 BsT[PBN][PLD];

    const int tid  = (int)threadIdx.x;
    const int w    = tid >> 6;
    const int lane = tid & 63;
    const int m16  = lane & 15;
    const int q    = lane >> 4;

    const int m0 = blockIdx.x * PBM;
    const int n0 = blockIdx.y * PBN;

    const int ar  = tid >> 3;
    const int acq = tid & 7;
    const int bn  = tid & 63;
    const int bko = (tid >> 6) * 8;

    f32x4 acc[4] = {};

    for (int k0 = 0; k0 < D_; k0 += 32) {
        const float4 a0 = *(const float4*)&A[(size_t)(m0 + ar) * D_ + k0 + 4 * acq];
        const float4 a1 = *(const float4*)&A[(size_t)(m0 + ar + 32) * D_ + k0 + 4 * acq];
        float bv[8];
        #pragma unroll
        for (int c = 0; c < 8; ++c)
            bv[c] = Bm[(size_t)(k0 + bko + c) * U_ + n0 + bn];

        __syncthreads();

        f16x4 av0 = {(_Float16)a0.x, (_Float16)a0.y, (_Float16)a0.z, (_Float16)a0.w};
        f16x4 av1 = {(_Float16)a1.x, (_Float16)a1.y, (_Float16)a1.z, (_Float16)a1.w};
        f16x8 bh;
        #pragma unroll
        for (int c = 0; c < 8; ++c) bh[c] = (_Float16)bv[c];
        *(f16x4*)&As[ar][4 * acq]      = av0;
        *(f16x4*)&As[ar + 32][4 * acq] = av1;
        *(f16x8*)&BsT[bn][bko]         = bh;

        __syncthreads();

        const f16x8 af = *(const f16x8*)&As[16 * w + m16][8 * q];
        #pragma unroll
        for (int nt = 0; nt < 4; ++nt) {
            const f16x8 bf = *(const f16x8*)&BsT[16 * nt + m16][8 * q];
            acc[nt] = __builtin_amdgcn_mfma_f32_16x16x32_f16(af, bf, acc[nt], 0, 0, 0);
        }
    }

    const int row0 = m0 + 16 * w + 4 * q;
    #pragma unroll
    for (int nt = 0; nt < 4; ++nt) {
        const float bb = bias[n0 + 16 * nt + m16];
        #pragma unroll
        for (int r = 0; r < 4; ++r)
            C[(size_t)(row0 + r) * U_ + n0 + 16 * nt + m16] = acc[nt][r] + bb;
    }
}

__device__ __forceinline__ float fast_tanh(float x) {
    float a = fminf(fabsf(x) * 2.0f, 20.0f);
    float e = __expf(a);
    float t = 1.0f - 2.0f * __builtin_amdgcn_rcpf(e + 1.0f);
    return copysignf(t, x);
}

// ---------------------------------------------------------------------------
// Kernel 2: MFMA recurrence. 4 blocks x 256 thr (4 waves, 1/SIMD via
// waves_per_eu(1,1) — spilling buys the allocator nothing, so the 128-VGPR
// W-fragment file should stay resident; VGPR_Count is the tell).
// Block bg owns batches [16bg,16bg+16) as MFMA M-dim:
//   H_{t+1}[16x256] = tanh(xW_t + H_t @ W_hh), via mfma_f32_16x16x32_f16.
// Wave g owns u-slice [64g,64g+64) = 4 n-tiles; B-frags Bf[8kc][4nt] loaded
// once (fragment mappings verified by R7's passing proj_gemm).
// H_t in LDS as Hlds[buf][m][264] f16 (A-frag layout, +8 pad, dbuffered);
// per step: 8x ds_read_b128 A-frags -> 32 MFMA -> 16 tanh -> global store +
// 16x ds_write_b16 transpose into Hlds[1-p]. xW prefetched one step ahead
// into registers (C-layout scalar loads; no LDS staging). One raw
// s_barrier/step (lgkmcnt only, no vmcnt drain).
// In-place safety: reads at (t+1)*U_+off vs writes at t*U_+off' can never
// alias (|off-off'| < U_).
// ---------------------------------------------------------------------------
#define HSTR 264   // f16 row stride: 256 + 8 pad

__global__ __launch_bounds__(256) __attribute__((amdgpu_waves_per_eu(1, 1)))
void rnn_scan(const float* __restrict__ W_hh,   // [U_, U_]
              float* __restrict__ out) {        // [B_, T_, U_]: xW in, h out
    const int bg   = (int)blockIdx.x;
    const int tid  = (int)threadIdx.x;
    const int g    = tid >> 6;        // wave: u-slice [64g, 64g+64)
    const int lane = tid & 63;
    const int m16  = lane & 15;
    const int q    = lane >> 4;

    __shared__ _Float16 Hlds[2][16][HSTR];

    // ---- one-time: W_hh B-fragments into 128 VGPRs.
    // Bf[c][nt][j] = W_hh[32c+8q+j][64g+16nt+m16]  (B[k][n] frag layout)
    f16x8 Bf[8][4];
    #pragma unroll
    for (int c = 0; c < 8; ++c)
        #pragma unroll
        for (int nt = 0; nt < 4; ++nt) {
            f16x8 v;
            #pragma unroll
            for (int j = 0; j < 8; ++j)
                v[j] = (_Float16)W_hh[(size_t)(32 * c + 8 * q + j) * U_ +
                                      64 * g + 16 * nt + m16];
            Bf[c][nt] = v;
        }

    // ---- zero H buffers
    {
        _Float16* hz = &Hlds[0][0][0];
        for (int i = tid; i < 2 * 16 * HSTR; i += 256) hz[i] = (_Float16)0.f;
    }

    // ---- per-(r) global row pointers (C-layout addressing)
    const float* __restrict__ dummy = out;  (void)dummy;
    float* pr[4];
    #pragma unroll
    for (int r = 0; r < 4; ++r)
        pr[r] = out + ((size_t)(bg * 16 + 4 * q + r) * T_) * U_ + 64 * g + m16;

    // prefetch xw for t=0
    float xwc[4][4], xwn[4][4];
    #pragma unroll
    for (int nt = 0; nt < 4; ++nt)
        #pragma unroll
        for (int r = 0; r < 4; ++r)
            xwc[nt][r] = pr[r][16 * nt];

    __syncthreads();

    for (int t = 0; t < T_; ++t) {
        const int p = t & 1;
        const size_t toff = (size_t)t * U_;

        // prefetch next step's xw (retires during this step's compute)
        if (t + 1 < T_) {
            #pragma unroll
            for (int nt = 0; nt < 4; ++nt)
                #pragma unroll
                for (int r = 0; r < 4; ++r)
                    xwn[nt][r] = pr[r][toff + U_ + 16 * nt];
        }

        // ---- A-frag stream + MFMA: acc[nt] init = xw (free add)
        f32x4 acc[4];
        #pragma unroll
        for (int nt = 0; nt < 4; ++nt)
            acc[nt] = (f32x4){xwc[nt][0], xwc[nt][1], xwc[nt][2], xwc[nt][3]};

        f16x8 a_cur = *(const f16x8*)&Hlds[p][m16][8 * q];
        #pragma unroll
        for (int c = 0; c < 8; ++c) {
            f16x8 a_nxt = a_cur;
            if (c < 7) a_nxt = *(const f16x8*)&Hlds[p][m16][32 * (c + 1) + 8 * q];
            #pragma unroll
            for (int nt = 0; nt < 4; ++nt)
                acc[nt] = __builtin_amdgcn_mfma_f32_16x16x32_f16(a_cur, Bf[c][nt],
                                                                 acc[nt], 0, 0, 0);
            a_cur = a_nxt;
        }

        // ---- epilogue: tanh, global store, LDS transpose write
        #pragma unroll
        for (int nt = 0; nt < 4; ++nt)
            #pragma unroll
            for (int r = 0; r < 4; ++r) {
                const float hn = fast_tanh(acc[nt][r]);
                pr[r][toff + 16 * nt] = hn;                       // h out (async)
                Hlds[1 - p][4 * q + r][64 * g + 16 * nt + m16] = (_Float16)hn;
            }

        #pragma unroll
        for (int nt = 0; nt < 4; ++nt)
            #pragma unroll
            for (int r = 0; r < 4; ++r)
                xwc[nt][r] = xwn[nt][r];

        // raw barrier: order LDS (writes -> next step's reads); no vmcnt drain
        __asm__ __volatile__("s_waitcnt lgkmcnt(0)\n\ts_barrier" ::: "memory");
    }
}

// ---------------------------------------------------------------------------
extern "C" void kernel_launch(void* const* d_in, const int* in_sizes, int n_in,
                              void* d_out, int out_size, void* d_ws, size_t ws_size,
                              hipStream_t stream) {
    const float* inputs = (const float*)d_in[0];   // [B, T, D]
    const float* W_xh   = (const float*)d_in[1];   // [D, U]
    const float* W_hh   = (const float*)d_in[2];   // [U, U]
    const float* b_h    = (const float*)d_in[3];   // [U]
    float* out = (float*)d_out;                    // [B, T, U]

    const int M = B_ * T_;                         // 65536
    dim3 g1(M / PBM, U_ / PBN);                    // (1024, 4)
    proj_gemm<<<g1, 256, 0, stream>>>(inputs, W_xh, b_h, out);
    rnn_scan<<<B_ / 16, 256, 0, stream>>>(W_hh, out);
}